// Round 14
// baseline (437.153 us; speedup 1.0000x reference)
//
#include <hip/hip_runtime.h>
#include <hip/hip_bf16.h>
#include <cmath>

#define T_DIM 2048
#define C_DIM 2048
#define NH    32
#define SS    64
#define NC    64    // chunks
#define CL    32    // chunk length

#define SWZ(r) (((r) + ((r) >> 2)) & 3)

// T4-lite (r11): counted vmcnt + raw barrier.
#define WAIT4_BARRIER() do { \
    asm volatile("s_waitcnt vmcnt(4)" ::: "memory"); \
    __builtin_amdgcn_s_barrier(); } while (0)

typedef unsigned short ushort_t;
typedef __attribute__((ext_vector_type(8))) short bf16x8;
typedef __attribute__((ext_vector_type(4))) float f32x4;

__device__ __forceinline__ ushort_t f2bf(float v) {
    union { __hip_bfloat16 b; ushort_t u; } cv;
    cv.b = __float2bfloat16(v);
    return cv.u;
}

__device__ __forceinline__ void gload_lds16(const void* g, void* l) {
    __builtin_amdgcn_global_load_lds((const __attribute__((address_space(1))) void*)g,
                                     (__attribute__((address_space(3))) void*)l,
                                     16, 0, 0);
}

// broadcast lane k's float to all lanes via SGPR (VALU, not LDS unit)
__device__ __forceinline__ float bcast(float x, int k) {
    return __int_as_float(__builtin_amdgcn_readlane(__float_as_int(x), k));
}

// ---------------------------------------------------------------------------
// MEGA-INIT (r8): all 12 weight cast+transposes + prep + state0 in ONE launch.
// ---------------------------------------------------------------------------
__global__ __launch_bounds__(256)
void mega_init(const float* __restrict__ W1, const float* __restrict__ Wd1,
               const float* __restrict__ Wd2, const float* __restrict__ Wq,
               const float* __restrict__ Wk, const float* __restrict__ Wv,
               const float* __restrict__ Wg, const float* __restrict__ W2,
               ushort_t* __restrict__ W1T, ushort_t* __restrict__ Wd1T,
               ushort_t* __restrict__ Wd2T, ushort_t* __restrict__ WqT,
               ushort_t* __restrict__ WkT, ushort_t* __restrict__ WvT,
               ushort_t* __restrict__ WgT, ushort_t* __restrict__ W2Tall,
               const float* __restrict__ x, const float* __restrict__ state,
               const unsigned char* __restrict__ ns, const float* __restrict__ tmx,
               float* __restrict__ sx, ushort_t* __restrict__ xxxb,
               const int* __restrict__ len, float* __restrict__ outstate) {
    __shared__ float t[32][33];
    int bx = blockIdx.x;
    int tid = threadIdx.x;

    if (bx < 4096) {                       // ---- prep job ----
        int i4 = bx * 256 + tid;
        int idx = i4 * 4;
        int tt = idx >> 11;
        int c = idx & 2047;
        float4 xv = *(const float4*)(x + idx);
        float4 prev;
        if (ns[tt]) prev = make_float4(0.f, 0.f, 0.f, 0.f);
        else if (tt == 0) prev = *(const float4*)(state + c);
        else prev = *(const float4*)(x + idx - C_DIM);
        float4 tm = *(const float4*)(tmx + c);
        float4 s4;
        s4.x = prev.x - xv.x;  s4.y = prev.y - xv.y;
        s4.z = prev.z - xv.z;  s4.w = prev.w - xv.w;
        *(float4*)(sx + idx) = s4;
        ushort4 xb;
        xb.x = f2bf(xv.x + s4.x * tm.x);
        xb.y = f2bf(xv.y + s4.y * tm.y);
        xb.z = f2bf(xv.z + s4.z * tm.z);
        xb.w = f2bf(xv.w + s4.w * tm.w);
        *(ushort4*)(xxxb + idx) = xb;
        return;
    }
    bx -= 4096;
    if (bx < 8) {                          // ---- state0 job ----
        int c = bx * 256 + tid;
        if (c < C_DIM)
            outstate[c] = x[(size_t)(len[0] - 1) * C_DIM + c];
        return;
    }
    bx -= 8;
    // ---- cast jobs ----
    const float* W; ushort_t* WT; int K, N, nx;
    if (bx < 512)        {            W = W1;  WT = W1T;  K = 2048; N = 160;  nx = 8;  }
    else if (bx < 768)   { bx -= 512; W = Wd1; WT = Wd1T; K = 2048; N = 64;   nx = 4;  }
    else if (bx < 896)   { bx -= 768; W = Wd2; WT = Wd2T; K = 64;   N = 2048; nx = 64; }
    else if (bx < 4992)  { bx -= 896; W = Wq;  WT = WqT;  K = 2048; N = 2048; nx = 64; }
    else if (bx < 6016)  { bx -= 4992; W = Wk; WT = WkT;  K = 2048; N = 512;  nx = 16; }
    else if (bx < 7040)  { bx -= 6016; W = Wv; WT = WvT;  K = 2048; N = 512;  nx = 16; }
    else if (bx < 11136) { bx -= 7040; W = Wg; WT = WgT;  K = 2048; N = 2048; nx = 64; }
    else {
        bx -= 11136;
        int br = bx >> 6; bx &= 63;
        W = W2 + (size_t)br * 32 * C_DIM; WT = W2Tall + (size_t)br * C_DIM * 32;
        K = 32; N = 2048; nx = 64;
    }
    int n0 = (bx % nx) * 32, k0 = (bx / nx) * 32;
    int tx = tid & 31, ty = tid >> 5;
    #pragma unroll
    for (int i = 0; i < 4; ++i) {
        int k = ty + i * 8;
        float v = 0.f;
        if (n0 + tx < N) v = W[(size_t)(k0 + k) * N + n0 + tx];
        t[k][tx] = v;
    }
    __syncthreads();
    #pragma unroll
    for (int i = 0; i < 4; ++i) {
        int n = ty + i * 8;
        WT[(size_t)(n0 + n) * K + k0 + tx] = f2bf(t[tx][n]);
    }
}

// ---------------------------------------------------------------------------
// W1 split-K (r10) + T4-lite counted vmcnt (r11).
// ---------------------------------------------------------------------------
__global__ __launch_bounds__(256)
void w1_splitk(const ushort_t* __restrict__ A,      // xxxb [2048][2048]
               const ushort_t* __restrict__ BT,     // W1T  [256][2048]
               float* __restrict__ Wp) {            // [8][2048][256]
    const int lda = 2048, K = 2048;
    __shared__ ushort_t As[3][128 * 32];
    __shared__ ushort_t Bs[3][128 * 32];
    int tid = threadIdx.x;
    int wave = tid >> 6, lane = tid & 63;
    int m0 = blockIdx.y * 128, n0 = blockIdx.x * 128;
    int kbase = blockIdx.z * 256;
    float* Cf = Wp + (size_t)blockIdx.z * 2048 * 256;
    int wm = wave >> 1, wn = wave & 1;

    f32x4 acc[4][4] = {};
    int srow0 = wave * 16 + (lane >> 2);
    int schunk = lane & 3;
    int row0 = srow0, row1 = 64 + srow0;
    int gch0 = schunk ^ SWZ(row0), gch1 = schunk ^ SWZ(row1);
    const ushort_t* gA0 = A + (size_t)(m0 + row0) * lda + kbase + gch0 * 8;
    const ushort_t* gA1 = A + (size_t)(m0 + row1) * lda + kbase + gch1 * 8;
    const ushort_t* gB0 = BT + (size_t)(n0 + row0) * K + kbase + gch0 * 8;
    const ushort_t* gB1 = BT + (size_t)(n0 + row1) * K + kbase + gch1 * 8;
    int l0 = row0 * 32 + schunk * 8;
    int l1 = row1 * 32 + schunk * 8;

    const int nt = 8;                      // 256 / 32
    gload_lds16(gA0, &As[0][l0]);
    gload_lds16(gB0, &Bs[0][l0]);
    gload_lds16(gA1, &As[0][l1]);
    gload_lds16(gB1, &Bs[0][l1]);
    gload_lds16(gA0 + 32, &As[1][l0]);
    gload_lds16(gB0 + 32, &Bs[1][l0]);
    gload_lds16(gA1 + 32, &As[1][l1]);
    gload_lds16(gB1 + 32, &Bs[1][l1]);
    WAIT4_BARRIER();

    int fr = lane & 15;
    int fc = lane >> 4;
    int cur = 0;
    for (int t = 0; t < nt; ++t) {
        if (t + 2 < nt) {
            int kk = (t + 2) << 5;
            int nb = cur == 0 ? 2 : cur - 1;      // (cur+2)%3
            gload_lds16(gA0 + kk, &As[nb][l0]);
            gload_lds16(gB0 + kk, &Bs[nb][l0]);
            gload_lds16(gA1 + kk, &As[nb][l1]);
            gload_lds16(gB1 + kk, &Bs[nb][l1]);
        }
        bf16x8 af[4], bfr[4];
        #pragma unroll
        for (int mi = 0; mi < 4; ++mi) {
            int r = wm * 64 + mi * 16 + fr;
            af[mi] = *(const bf16x8*)(&As[cur][r * 32 + ((fc ^ SWZ(r)) * 8)]);
        }
        #pragma unroll
        for (int ni = 0; ni < 4; ++ni) {
            int c = wn * 64 + ni * 16 + fr;
            bfr[ni] = *(const bf16x8*)(&Bs[cur][c * 32 + ((fc ^ SWZ(c)) * 8)]);
        }
        #pragma unroll
        for (int mi = 0; mi < 4; ++mi)
            #pragma unroll
            for (int ni = 0; ni < 4; ++ni)
                acc[mi][ni] = __builtin_amdgcn_mfma_f32_16x16x32_bf16(
                    af[mi], bfr[ni], acc[mi][ni], 0, 0, 0);
        WAIT4_BARRIER();
        cur = cur == 2 ? 0 : cur + 1;
    }

    int colin = lane & 15;
    int rquad = lane >> 4;
    #pragma unroll
    for (int mi = 0; mi < 4; ++mi)
        #pragma unroll
        for (int reg = 0; reg < 4; ++reg) {
            int row = m0 + wm * 64 + mi * 16 + rquad * 4 + reg;
            #pragma unroll
            for (int ni = 0; ni < 4; ++ni) {
                int col = n0 + wn * 64 + ni * 16 + colin;
                Cf[(size_t)row * 256 + col] = acc[mi][ni][reg];
            }
        }
}

__global__ __launch_bounds__(256)
void w1_reduce(const float* __restrict__ Wp, ushort_t* __restrict__ mtlb) {
    int idx = (blockIdx.x * 256 + threadIdx.x) * 4;   // 512 blocks cover 2048*256
    float4 s = *(const float4*)(Wp + idx);
    #pragma unroll
    for (int z = 1; z < 8; ++z) {
        float4 p = *(const float4*)(Wp + (size_t)z * 2048 * 256 + idx);
        s.x += p.x; s.y += p.y; s.z += p.z; s.w += p.w;
    }
    ushort4 o;
    o.x = f2bf(tanhf(s.x)); o.y = f2bf(tanhf(s.y));
    o.z = f2bf(tanhf(s.z)); o.w = f2bf(tanhf(s.w));
    *(ushort4*)(mtlb + idx) = o;
}

// ---------------------------------------------------------------------------
// Wo GEMM split-K x2 (r12): partials into the dead U region, then reduce.
// ---------------------------------------------------------------------------
__global__ __launch_bounds__(256)
void gemm_wo_splitk(const ushort_t* __restrict__ A, const ushort_t* __restrict__ BT,
                    float* __restrict__ Wp2) {
    const int lda = 2048, K = 2048;
    __shared__ ushort_t As[3][128 * 32];
    __shared__ ushort_t Bs[3][128 * 32];
    int tid = threadIdx.x;
    int wave = tid >> 6, lane = tid & 63;
    int id = blockIdx.y * 16 + blockIdx.x;
    int xcd = id & 7, j = id >> 3;
    int m0 = ((xcd >> 1) * 4 + (j & 3)) * 128;
    int n0 = ((xcd & 1) * 8 + (j >> 2)) * 128;
    int kbase = blockIdx.z * 1024;
    float* Cf = Wp2 + (size_t)blockIdx.z * 2048 * 2048;
    int wm = wave >> 1, wn = wave & 1;

    f32x4 acc[4][4] = {};
    int srow0 = wave * 16 + (lane >> 2);
    int schunk = lane & 3;
    int row0 = srow0, row1 = 64 + srow0;
    int gch0 = schunk ^ SWZ(row0), gch1 = schunk ^ SWZ(row1);
    const ushort_t* gA0 = A + (size_t)(m0 + row0) * lda + kbase + gch0 * 8;
    const ushort_t* gA1 = A + (size_t)(m0 + row1) * lda + kbase + gch1 * 8;
    const ushort_t* gB0 = BT + (size_t)(n0 + row0) * K + kbase + gch0 * 8;
    const ushort_t* gB1 = BT + (size_t)(n0 + row1) * K + kbase + gch1 * 8;
    int l0 = row0 * 32 + schunk * 8;
    int l1 = row1 * 32 + schunk * 8;

    const int nt = 32;                     // 1024 / 32
    gload_lds16(gA0, &As[0][l0]);
    gload_lds16(gB0, &Bs[0][l0]);
    gload_lds16(gA1, &As[0][l1]);
    gload_lds16(gB1, &Bs[0][l1]);
    gload_lds16(gA0 + 32, &As[1][l0]);
    gload_lds16(gB0 + 32, &Bs[1][l0]);
    gload_lds16(gA1 + 32, &As[1][l1]);
    gload_lds16(gB1 + 32, &Bs[1][l1]);
    WAIT4_BARRIER();

    int fr = lane & 15;
    int fc = lane >> 4;
    int cur = 0;
    for (int t = 0; t < nt; ++t) {
        if (t + 2 < nt) {
            int kk = (t + 2) << 5;
            int nb = cur == 0 ? 2 : cur - 1;
            gload_lds16(gA0 + kk, &As[nb][l0]);
            gload_lds16(gB0 + kk, &Bs[nb][l0]);
            gload_lds16(gA1 + kk, &As[nb][l1]);
            gload_lds16(gB1 + kk, &Bs[nb][l1]);
        }
        bf16x8 af[4], bfr[4];
        #pragma unroll
        for (int mi = 0; mi < 4; ++mi) {
            int r = wm * 64 + mi * 16 + fr;
            af[mi] = *(const bf16x8*)(&As[cur][r * 32 + ((fc ^ SWZ(r)) * 8)]);
        }
        #pragma unroll
        for (int ni = 0; ni < 4; ++ni) {
            int c = wn * 64 + ni * 16 + fr;
            bfr[ni] = *(const bf16x8*)(&Bs[cur][c * 32 + ((fc ^ SWZ(c)) * 8)]);
        }
        #pragma unroll
        for (int mi = 0; mi < 4; ++mi)
            #pragma unroll
            for (int ni = 0; ni < 4; ++ni)
                acc[mi][ni] = __builtin_amdgcn_mfma_f32_16x16x32_bf16(
                    af[mi], bfr[ni], acc[mi][ni], 0, 0, 0);
        WAIT4_BARRIER();
        cur = cur == 2 ? 0 : cur + 1;
    }

    int colin = lane & 15;
    int rquad = lane >> 4;
    #pragma unroll
    for (int mi = 0; mi < 4; ++mi)
        #pragma unroll
        for (int reg = 0; reg < 4; ++reg) {
            int row = m0 + wm * 64 + mi * 16 + rquad * 4 + reg;
            #pragma unroll
            for (int ni = 0; ni < 4; ++ni) {
                int col = n0 + wn * 64 + ni * 16 + colin;
                Cf[(size_t)row * 2048 + col] = acc[mi][ni][reg];
            }
        }
}

__global__ __launch_bounds__(256)
void wo_reduce(const float* __restrict__ Wp2, float* __restrict__ out) {
    int idx = (blockIdx.x * 256 + threadIdx.x) * 4;   // 4096 blocks cover 2048*2048
    float4 a = *(const float4*)(Wp2 + idx);
    float4 b = *(const float4*)(Wp2 + (size_t)2048 * 2048 + idx);
    a.x += b.x; a.y += b.y; a.z += b.z; a.w += b.w;
    *(float4*)(out + idx) = a;
}

// ---------------------------------------------------------------------------
// FUSED projections (r7) + XCD swizzle (r9) + T4-lite counted vmcnt (r11).
// ---------------------------------------------------------------------------
__global__ __launch_bounds__(256)
void gemm_fused5(const ushort_t* __restrict__ xw, const ushort_t* __restrict__ xk,
                 const ushort_t* __restrict__ xv, const ushort_t* __restrict__ xr,
                 const ushort_t* __restrict__ xg,
                 const ushort_t* __restrict__ Wd1T, const ushort_t* __restrict__ WkT,
                 const ushort_t* __restrict__ WvT, const ushort_t* __restrict__ WqT,
                 const ushort_t* __restrict__ WgT,
                 ushort_t* __restrict__ tw, float* __restrict__ k0g,
                 float* __restrict__ v0g, float* __restrict__ rg,
                 float* __restrict__ gg) {
    const int K = 2048, lda = 2048;
    int id = blockIdx.y * 41 + blockIdx.x;     // 0..655
    int swz = (id & 7) * 82 + (id >> 3);       // XCD strip, 656 = 8*82
    int bx = swz >> 4;
    int m0 = (swz & 15) * 128;

    const ushort_t* A; const ushort_t* BT;
    float* Cf = nullptr; ushort_t* Cb = nullptr;
    int ldc, n0, epi;
    if (bx == 0)       { A = xw; BT = Wd1T; Cb = tw;  ldc = 128;  n0 = 0;               epi = 4; }
    else if (bx < 5)   { A = xk; BT = WkT;  Cf = k0g; ldc = 512;  n0 = (bx - 1) * 128;  epi = 0; }
    else if (bx < 9)   { A = xv; BT = WvT;  Cf = v0g; ldc = 512;  n0 = (bx - 5) * 128;  epi = 0; }
    else if (bx < 25)  { A = xr; BT = WqT;  Cf = rg;  ldc = 2048; n0 = (bx - 9) * 128;  epi = 0; }
    else               { A = xg; BT = WgT;  Cf = gg;  ldc = 2048; n0 = (bx - 25) * 128; epi = 2; }

    __shared__ ushort_t As[3][128 * 32];
    __shared__ ushort_t Bs[3][128 * 32];
    int tid = threadIdx.x;
    int wave = tid >> 6, lane = tid & 63;
    int wm = wave >> 1, wn = wave & 1;

    f32x4 acc[4][4] = {};
    int srow0 = wave * 16 + (lane >> 2);
    int schunk = lane & 3;
    int row0 = srow0, row1 = 64 + srow0;
    int gch0 = schunk ^ SWZ(row0), gch1 = schunk ^ SWZ(row1);
    const ushort_t* gA0 = A + (size_t)(m0 + row0) * lda + gch0 * 8;
    const ushort_t* gA1 = A + (size_t)(m0 + row1) * lda + gch1 * 8;
    const ushort_t* gB0 = BT + (size_t)(n0 + row0) * K + gch0 * 8;
    const ushort_t* gB1 = BT + (size_t)(n0 + row1) * K + gch1 * 8;
    int l0 = row0 * 32 + schunk * 8;
    int l1 = row1 * 32 + schunk * 8;

    const int nt = K >> 5;
    gload_lds16(gA0, &As[0][l0]);
    gload_lds16(gB0, &Bs[0][l0]);
    gload_lds16(gA1, &As[0][l1]);
    gload_lds16(gB1, &Bs[0][l1]);
    gload_lds16(gA0 + 32, &As[1][l0]);
    gload_lds16(gB0 + 32, &Bs[1][l0]);
    gload_lds16(gA1 + 32, &As[1][l1]);
    gload_lds16(gB1 + 32, &Bs[1][l1]);
    WAIT4_BARRIER();

    int fr = lane & 15;
    int fc = lane >> 4;
    int cur = 0;
    for (int t = 0; t < nt; ++t) {
        if (t + 2 < nt) {
            int kk = (t + 2) << 5;
            int nb = cur == 0 ? 2 : cur - 1;
            gload_lds16(gA0 + kk, &As[nb][l0]);
            gload_lds16(gB0 + kk, &Bs[nb][l0]);
            gload_lds16(gA1 + kk, &As[nb][l1]);
            gload_lds16(gB1 + kk, &Bs[nb][l1]);
        }
        bf16x8 af[4], bfr[4];
        #pragma unroll
        for (int mi = 0; mi < 4; ++mi) {
            int r = wm * 64 + mi * 16 + fr;
            af[mi] = *(const bf16x8*)(&As[cur][r * 32 + ((fc ^ SWZ(r)) * 8)]);
        }
        #pragma unroll
        for (int ni = 0; ni < 4; ++ni) {
            int c = wn * 64 + ni * 16 + fr;
            bfr[ni] = *(const bf16x8*)(&Bs[cur][c * 32 + ((fc ^ SWZ(c)) * 8)]);
        }
        #pragma unroll
        for (int mi = 0; mi < 4; ++mi)
            #pragma unroll
            for (int ni = 0; ni < 4; ++ni)
                acc[mi][ni] = __builtin_amdgcn_mfma_f32_16x16x32_bf16(
                    af[mi], bfr[ni], acc[mi][ni], 0, 0, 0);
        WAIT4_BARRIER();
        cur = cur == 2 ? 0 : cur + 1;
    }

    int colin = lane & 15;
    int rquad = lane >> 4;
    #pragma unroll
    for (int mi = 0; mi < 4; ++mi) {
        #pragma unroll
        for (int reg = 0; reg < 4; ++reg) {
            int row = m0 + wm * 64 + mi * 16 + rquad * 4 + reg;
            #pragma unroll
            for (int ni = 0; ni < 4; ++ni) {
                int col = n0 + wn * 64 + ni * 16 + colin;
                float v = acc[mi][ni][reg];
                if (epi == 2) v = 1.f / (1.f + __expf(-v));
                else if (epi == 4) v = tanhf(v);
                if (epi == 4) Cb[(size_t)row * ldc + col] = f2bf(v);
                else          Cf[(size_t)row * ldc + col] = v;
            }
        }
    }
}

// ---------------------------------------------------------------------------
// dec GEMM + Wo cast fused (r9).
// ---------------------------------------------------------------------------
__global__ __launch_bounds__(256)
void dec_cast(const ushort_t* __restrict__ tw, const ushort_t* __restrict__ Wd2T,
              const float* __restrict__ tdec, float* __restrict__ dec,
              const float* __restrict__ Wo, ushort_t* __restrict__ WoT) {
    int id = blockIdx.x;
    int tid = threadIdx.x;
    if (id >= 256) {                       // ---- Wo cast tile ----
        __shared__ float t[32][33];
        int c = id - 256;
        int n0 = (c & 63) * 32, k0 = (c >> 6) * 32;
        int tx = tid & 31, ty = tid >> 5;
        #pragma unroll
        for (int i = 0; i < 4; ++i) {
            int k = ty + i * 8;
            t[k][tx] = Wo[(size_t)(k0 + k) * 2048 + n0 + tx];
        }
        __syncthreads();
        #pragma unroll
        for (int i = 0; i < 4; ++i) {
            int n = ty + i * 8;
            WoT[(size_t)(n0 + n) * 2048 + k0 + tx] = f2bf(t[tx][n]);
        }
        return;
    }
    const int K = 64, lda = 128, ldc = 2048;
    __shared__ ushort_t As[2][128 * 32];
    __shared__ ushort_t Bs[2][128 * 32];
    int wave = tid >> 6, lane = tid & 63;
    int m0 = (id >> 4) * 128, n0 = (id & 15) * 128;
    int wm = wave >> 1, wn = wave & 1;

    f32x4 acc[4][4] = {};
    int srow0 = wave * 16 + (lane >> 2);
    int schunk = lane & 3;
    int row0 = srow0, row1 = 64 + srow0;
    int gch0 = schunk ^ SWZ(row0), gch1 = schunk ^ SWZ(row1);
    const ushort_t* gA0 = tw + (size_t)(m0 + row0) * lda + gch0 * 8;
    const ushort_t* gA1 = tw + (size_t)(m0 + row1) * lda + gch1 * 8;
    const ushort_t* gB0 = Wd2T + (size_t)(n0 + row0) * K + gch0 * 8;
    const ushort_t* gB1 = Wd2T + (size_t)(n0 + row1) * K + gch1 * 8;
    int l0 = row0 * 32 + schunk * 8;
    int l1 = row1 * 32 + schunk * 8;

    const int nt = K >> 5;                 // = 2
    gload_lds16(gA0, &As[0][l0]);
    gload_lds16(gB0, &Bs[0][l0]);
    gload_lds16(gA1, &As[0][l1]);
    gload_lds16(gB1, &Bs[0][l1]);
    __syncthreads();

    int fr = lane & 15;
    int fc = lane >> 4;
    int cur = 0;
    for (int t = 0; t < nt; ++t) {
        if (t + 1 < nt) {
            int kk = (t + 1) << 5;
            gload_lds16(gA0 + kk, &As[cur ^ 1][l0]);
            gload_lds16(gB0 + kk, &Bs[cur ^ 1][l0]);
            gload_lds16(gA1 + kk, &As[cur ^ 1][l1]);
            gload_lds16(gB1 + kk, &Bs[cur ^ 1][l1]);
        }
        bf16x8 af[4], bfr[4];
        #pragma unroll
        for (int mi = 0; mi < 4; ++mi) {
            int r = wm * 64 + mi * 16 + fr;
            af[mi] = *(const bf16x8*)(&As[cur][r * 32 + ((fc ^ SWZ(r)) * 8)]);
        }
        #pragma unroll
        for (int ni = 0; ni < 4; ++ni) {
            int c = wn * 64 + ni * 16 + fr;
            bfr[ni] = *(const bf16x8*)(&Bs[cur][c * 32 + ((fc ^ SWZ(c)) * 8)]);
        }
        #pragma unroll
        for (int mi = 0; mi < 4; ++mi)
            #pragma unroll
            for (int ni = 0; ni < 4; ++ni)
                acc[mi][ni] = __builtin_amdgcn_mfma_f32_16x16x32_bf16(
                    af[mi], bfr[ni], acc[mi][ni], 0, 0, 0);
        __syncthreads();
        cur ^= 1;
    }

    int colin = lane & 15;
    int rquad = lane >> 4;
    #pragma unroll
    for (int mi = 0; mi < 4; ++mi)
        #pragma unroll
        for (int reg = 0; reg < 4; ++reg) {
            int row = m0 + wm * 64 + mi * 16 + rquad * 4 + reg;
            #pragma unroll
            for (int ni = 0; ni < 4; ++ni) {
                int col = n0 + wn * 64 + ni * 16 + colin;
                dec[(size_t)row * ldc + col] = acc[mi][ni][reg] + tdec[col];
            }
        }
}

// ---------------------------------------------------------------------------
// LoRA-combine (r14): ONE block per (m0,n0) tile loops all 5 branches.
// The 5 branch epilogues read the SAME x/sx 128x128 tiles; looping inside
// one block makes reads 2-5 L2 hits -> HBM traffic ~200->~98 MB.
// #pragma unroll makes br compile-time (static tm/dst, rule #20 safe).
// ---------------------------------------------------------------------------
__global__ __launch_bounds__(256)
void maa_gemm(const ushort_t* __restrict__ mtlb,      // [T,256] bf16 tanh
              const ushort_t* __restrict__ W2Tall,    // [5][C][32] bf16
              const float* __restrict__ x, const float* __restrict__ sx,
              const float* __restrict__ tmr, const float* __restrict__ tmk,
              const float* __restrict__ tmv, const float* __restrict__ tmw,
              const float* __restrict__ tmg,
              ushort_t* __restrict__ xr, ushort_t* __restrict__ xk,
              ushort_t* __restrict__ xv, ushort_t* __restrict__ xw,
              ushort_t* __restrict__ xg) {
    __shared__ ushort_t As[128 * 32];
    __shared__ ushort_t Bs[128 * 32];
    int tid = threadIdx.x;
    int wave = tid >> 6, lane = tid & 63;
    int m0 = blockIdx.y * 128, n0 = blockIdx.x * 128;
    int wm = wave >> 1, wn = wave & 1;
    int srow0 = wave * 16 + (lane >> 2);
    int schunk = lane & 3;
    int fr = lane & 15;
    int fc = lane >> 4;
    int colin = lane & 15;
    int rquad = lane >> 4;

    #pragma unroll
    for (int br = 0; br < 5; ++br) {
        const float* tm; ushort_t* dst;
        if      (br == 0) { tm = tmr; dst = xr; }
        else if (br == 1) { tm = tmk; dst = xk; }
        else if (br == 2) { tm = tmv; dst = xv; }
        else if (br == 3) { tm = tmw; dst = xw; }
        else              { tm = tmg; dst = xg; }
        const ushort_t* BT = W2Tall + (size_t)br * C_DIM * 32;

        #pragma unroll
        for (int j = 0; j < 2; ++j) {
            int row = j * 64 + srow0;
            int gch = schunk ^ SWZ(row);
            gload_lds16(mtlb + (size_t)(m0 + row) * 256 + br * 32 + gch * 8,
                        As + row * 32 + schunk * 8);
            gload_lds16(BT + (size_t)(n0 + row) * 32 + gch * 8,
                        Bs + row * 32 + schunk * 8);
        }
        __syncthreads();

        f32x4 acc[4][4] = {};
        bf16x8 af[4], bfr[4];
        #pragma unroll
        for (int mi = 0; mi < 4; ++mi) {
            int r = wm * 64 + mi * 16 + fr;
            af[mi] = *(const bf16x8*)(As + r * 32 + ((fc ^ SWZ(r)) * 8));
        }
        #pragma unroll
        for (int ni = 0; ni < 4; ++ni) {
            int c = wn * 64 + ni * 16 + fr;
            bfr[ni] = *(const bf16x8*)(Bs + c * 32 + ((fc ^ SWZ(c)) * 8));
        }
        #pragma unroll
        for (int mi = 0; mi < 4; ++mi)
            #pragma unroll
            for (int ni = 0; ni < 4; ++ni)
                acc[mi][ni] = __builtin_amdgcn_mfma_f32_16x16x32_bf16(
                    af[mi], bfr[ni], acc[mi][ni], 0, 0, 0);
        __syncthreads();   // frag reads done before next branch's staging

        #pragma unroll
        for (int mi = 0; mi < 4; ++mi) {
            #pragma unroll
            for (int reg = 0; reg < 4; ++reg) {
                int row = m0 + wm * 64 + mi * 16 + rquad * 4 + reg;
                #pragma unroll
                for (int ni = 0; ni < 4; ++ni) {
                    int col = n0 + wn * 64 + ni * 16 + colin;
                    size_t idx = (size_t)row * C_DIM + col;
                    float m = acc[mi][ni][reg];
                    dst[idx] = f2bf(x[idx] + sx[idx] * (tm[col] + m));
                }
            }
        }
    }
}

// ---------------------------------------------------------------------------
// Chunked scan pass 1 (r11 version): single wave, readlane bcast.
// ---------------------------------------------------------------------------
__global__ __launch_bounds__(64)
void scan_pass1(const float* __restrict__ k0, const float* __restrict__ v0,
                const float* __restrict__ dec, const unsigned char* __restrict__ ns,
                float* __restrict__ U, float* __restrict__ P) {
    int h = blockIdx.x, c = blockIdx.y, v = threadIdx.x;
    int hk = h >> 2;
    float u[64];
    #pragma unroll
    for (int k = 0; k < 64; ++k) u[k] = 0.f;
    float pk = 1.f;
    int t0 = c * CL;
    float dv_n = dec[(size_t)t0 * 2048 + h * 64 + v];
    float kv_n = k0[(size_t)t0 * 512 + hk * 64 + v];
    float vv_n = v0[(size_t)t0 * 512 + hk * 64 + v];
    unsigned char ns_n = ns[t0];
    for (int i = 0; i < CL; ++i) {
        float dv = dv_n, kv = kv_n, vv = vv_n;
        unsigned char nsv = ns_n;
        if (i + 1 < CL) {
            int t = t0 + i + 1;
            dv_n = dec[(size_t)t * 2048 + h * 64 + v];
            kv_n = k0[(size_t)t * 512 + hk * 64 + v];
            vv_n = v0[(size_t)t * 512 + hk * 64 + v];
            ns_n = ns[t];
        }
        float lw = fmaxf(-__expf(dv), -5.f);
        float ew = __expf(lw);
        float ewp = nsv ? 0.f : ew;
        float kk = kv * (1.f - ew);
        pk *= ewp;
        #pragma unroll
        for (int k = 0; k < 64; ++k) {
            float ewk = bcast(ewp, k);
            float kkk = bcast(kk, k);
            u[k] = fmaf(u[k], ewk, kkk * vv);
        }
    }
    size_t base = ((size_t)h * NC + c) * 4096;
    #pragma unroll
    for (int k = 0; k < 64; ++k) U[base + k * 64 + v] = u[k];
    P[((size_t)h * NC + c) * 64 + v] = pk;
}

// ---------------------------------------------------------------------------
// Pass 2 (elementwise-parallel): one thread per (h,k,v) state element.
// ---------------------------------------------------------------------------
__global__ __launch_bounds__(256)
void scan_pass2(float* __restrict__ U, const float* __restrict__ P,
                const float* __restrict__ state, float* __restrict__ outstate) {
    int e = blockIdx.x * 256 + threadIdx.x;      // e = h*4096 + k*64 + v
    int h = e >> 12;
    int k = (e >> 6) & 63;
    float s = state[C_DIM + e];
    int rem = e & 4095;
    #pragma unroll 4
    for (int c = 0; c < NC; ++c) {
        size_t ub = ((size_t)h * NC + c) * 4096 + rem;
        float p = P[((size_t)h * NC + c) * 64 + k];
        float u = U[ub];
        U[ub] = s;
        s = fmaf(s, p, u);
    }
    outstate[C_DIM + e] = s;
}

// ---------------------------------------------------------------------------
// Pass 3 (r11 version): single wave, readlane bcast, 4 partials.
// ---------------------------------------------------------------------------
__global__ __launch_bounds__(64)
void scan_pass3(const float* __restrict__ r, const float* __restrict__ k0,
                const float* __restrict__ v0, const float* __restrict__ dec,
                const unsigned char* __restrict__ ns,
                const float* __restrict__ Sstarts, const float* __restrict__ g,
                ushort_t* __restrict__ y0b) {
    int h = blockIdx.x, c = blockIdx.y, v = threadIdx.x;
    int hk = h >> 2;
    float s[64];
    size_t base = ((size_t)h * NC + c) * 4096;
    #pragma unroll
    for (int k = 0; k < 64; ++k) s[k] = Sstarts[base + k * 64 + v];
    int t0 = c * CL;
    float dv_n = dec[(size_t)t0 * 2048 + h * 64 + v];
    float kv_n = k0[(size_t)t0 * 512 + hk * 64 + v];
    float vv_n = v0[(size_t)t0 * 512 + hk * 64 + v];
    float rr_n = r[(size_t)t0 * 2048 + h * 64 + v];
    float gg_n = g[(size_t)t0 * 2048 + h * 64 + v];
    unsigned char ns_n = ns[t0];
    for (int i = 0; i < CL; ++i) {
        float dv = dv_n, kv = kv_n, vv = vv_n, rr = rr_n, gg = gg_n;
        unsigned char nsv = ns_n;
        if (i + 1 < CL) {
            int t = t0 + i + 1;
            dv_n = dec[(size_t)t * 2048 + h * 64 + v];
            kv_n = k0[(size_t)t * 512 + hk * 64 + v];
            vv_n = v0[(size_t)t * 512 + hk * 64 + v];
            rr_n = r[(size_t)t * 2048 + h * 64 + v];
            gg_n = g[(size_t)t * 2048 + h * 64 + v];
            ns_n = ns[t];
        }
        float lw = fmaxf(-__expf(dv), -5.f);
        float ew = __expf(lw);
        float ewl = nsv ? 0.f : ew;
        float kkl = kv * (1.f - ew);
        float o0 = 0.f, o1 = 0.f, o2 = 0.f, o3 = 0.f;
        #pragma unroll
        for (int k = 0; k < 64; k += 4) {
            float s0 = fmaf(s[k],     bcast(ewl, k),     bcast(kkl, k)     * vv); s[k]     = s0; o0 = fmaf(bcast(rr, k),     s0, o0);
            float s1 = fmaf(s[k + 1], bcast(ewl, k + 1), bcast(kkl, k + 1) * vv); s[k + 1] = s1; o1 = fmaf(bcast(rr, k + 1), s1, o1);
            float s2 = fmaf(s[k + 2], bcast(ewl, k + 2), bcast(kkl, k + 2) * vv); s[k + 2] = s2; o2 = fmaf(bcast(rr, k + 2), s2, o2);
            float s3 = fmaf(s[k + 3], bcast(ewl, k + 3), bcast(kkl, k + 3) * vv); s[k + 3] = s3; o3 = fmaf(bcast(rr, k + 3), s3, o3);
        }
        float o = (o0 + o1) + (o2 + o3);
        size_t idx = (size_t)(t0 + i) * 2048 + h * 64 + v;
        y0b[idx] = f2bf(o * gg);
    }
}

// ---------------------------------------------------------------------------
extern "C" void kernel_launch(void* const* d_in, const int* in_sizes, int n_in,
                              void* d_out, int out_size, void* d_ws, size_t ws_size,
                              hipStream_t stream) {
    const float* x     = (const float*)d_in[0];
    const float* state = (const float*)d_in[1];
    const unsigned char* ns = (const unsigned char*)d_in[2];
    const int*   len   = (const int*)d_in[3];
    const float* tmx   = (const float*)d_in[4];
    const float* tmr   = (const float*)d_in[5];
    const float* tmk   = (const float*)d_in[6];
    const float* tmv   = (const float*)d_in[7];
    const float* tmw   = (const float*)d_in[8];
    const float* tmg   = (const float*)d_in[9];
    const float* W1    = (const float*)d_in[10];   // [C,160]
    const float* W2    = (const float*)d_in[11];   // [5,32,C]
    const float* tdec  = (const float*)d_in[12];   // [C]
    const float* Wd1   = (const float*)d_in[13];   // [C,64]
    const float* Wd2   = (const float*)d_in[14];   // [64,C]
    const float* Wq    = (const float*)d_in[15];
    const float* Wk    = (const float*)d_in[16];
    const float* Wv    = (const float*)d_in[17];
    const float* Wg    = (const float*)d_in[18];
    const float* Wo    = (const float*)d_in[19];

    float* out = (float*)d_out;
    float* outstate = out + (size_t)T_DIM * C_DIM;

    // ---- workspace layout (r14; byte offsets; 122 MB total, aliased) ----
    char* wsb = (char*)d_ws;
    const size_t MB = 1024 * 1024;
    float*    sx   = (float*)(wsb + 0);            // 16 MB (dead after maa)
    float*    g    = (float*)(wsb + 0);            // 16 MB over sx
    ushort_t* xxxb = (ushort_t*)(wsb + 16 * MB);   // 8 MB; later y0b
    ushort_t* mtlb = (ushort_t*)(wsb + 24 * MB);   // 1 MB
    ushort_t* tw   = (ushort_t*)(wsb + 25 * MB);   // 0.5 MB
    float*    P    = (float*)(wsb + 25 * MB + 512 * 1024);  // 512 KB
    ushort_t* xr   = (ushort_t*)(wsb + 26 * MB);   // 8 MB (dead after fused5)
    ushort_t* xk   = (ushort_t*)(wsb + 34 * MB);   // 8 MB (dead after fused5)
    float*    dec  = (float*)(wsb + 26 * MB);      // 16 MB over xr+xk
    ushort_t* xv   = (ushort_t*)(wsb + 42 * MB);   // 8 MB (dead after fused5)
    ushort_t* WoT  = (ushort_t*)(wsb + 42 * MB);   // 8 MB over xv
    ushort_t* xw   = (ushort_t*)(wsb + 50 * MB);   // 8 MB
    ushort_t* xg   = (ushort_t*)(wsb + 58 * MB);   // 8 MB  (ends 66)
    float*    r    = (float*)(wsb + 66 * MB);      // 16 MB
    float*    Wp   = (float*)(wsb + 66 * MB);      // 16 MB over r (pre-fused5)
    float*    k0   = (float*)(wsb + 82 * MB);      // 4 MB
    float*    v0   = (float*)(wsb + 86 * MB);      // 4 MB
    ushort_t* WqT  = (ushort_t*)(wsb + 90 * MB);   // 8 MB
    ushort_t* WkT  = (ushort_t*)(wsb + 98 * MB);   // 2 MB
    ushort_t* WvT  = (ushort_t*)(wsb + 100 * MB);  // 2 MB
    ushort_t* W1T  = (ushort_t*)(wsb + 102 * MB);  // 1 MB
    ushort_t* Wd1T = (ushort_t*)(wsb + 103 * MB);  // 0.5 MB
    ushort_t* Wd2T = (ushort_t*)(wsb + 103 * MB + 512 * 1024); // 0.25 MB
    ushort_t* W2Tall = (ushort_t*)(wsb + 104 * MB); // 640 KB
    ushort_t* WgT  = (ushort_t*)(wsb + 106 * MB);  // 8 MB
    float*    U    = (float*)(wsb + 90 * MB);      // 32 MB over 90..122
    float*    Wp2  = (float*)(wsb + 90 * MB);      // 32 MB over U (post-pass3)
    ushort_t* y0b  = xxxb;

    dim3 blk(256);

    // ---- ONE init launch: 12 casts + prep + state0 ----
    mega_init<<<dim3(15560), blk, 0, stream>>>(
        W1, Wd1, Wd2, Wq, Wk, Wv, Wg, W2,
        W1T, Wd1T, Wd2T, WqT, WkT, WvT, WgT, W2Tall,
        x, state, ns, tmx, sx, xxxb, len, outstate);

    // ---- W1 LoRA via split-K ----
    w1_splitk<<<dim3(2, 16, 8), blk, 0, stream>>>(xxxb, W1T, Wp);
    w1_reduce<<<dim3(512), blk, 0, stream>>>(Wp, mtlb);
    // ---- LoRA-combine: 5 branches per block (x/sx read once) ----
    maa_gemm<<<dim3(16, 16), blk, 0, stream>>>(mtlb, W2Tall, x, sx,
                                               tmr, tmk, tmv, tmw, tmg,
                                               xr, xk, xv, xw, xg);
    // ---- FUSED independent projections (XCD swizzled, counted vmcnt) ----
    gemm_fused5<<<dim3(41, 16), blk, 0, stream>>>(xw, xk, xv, xr, xg,
                                                  Wd1T, WkT, WvT, WqT, WgT,
                                                  tw, k0, v0, r, g);
    // ---- dec GEMM + Wo cast in one launch ----
    dec_cast<<<dim3(4352), blk, 0, stream>>>(tw, Wd2T, tdec, dec, Wo, WoT);
    // ---- chunked scan (single-wave r11 versions) ----
    scan_pass1<<<dim3(NH, NC), dim3(64), 0, stream>>>(k0, v0, dec, ns, U, P);
    scan_pass2<<<dim3(512), blk, 0, stream>>>(U, P, state, outstate);
    scan_pass3<<<dim3(NH, NC), dim3(64), 0, stream>>>(r, k0, v0, dec, ns, U, g, y0b);
    // ---- output: split-K x2 into dead U region, then reduce ----
    gemm_wo_splitk<<<dim3(16, 16, 2), blk, 0, stream>>>(y0b, WoT, Wp2);
    wo_reduce<<<dim3(4096), blk, 0, stream>>>(Wp2, out);
}

// Round 16
// 421.309 us; speedup vs baseline: 1.0376x; 1.0376x over previous
//
#include <hip/hip_runtime.h>
#include <hip/hip_bf16.h>
#include <cmath>

#define T_DIM 2048
#define C_DIM 2048
#define NH    32
#define SS    64
#define NC    64    // chunks
#define CL    32    // chunk length

#define SWZ(r) (((r) + ((r) >> 2)) & 3)

// T4-lite (r11): counted vmcnt + raw barrier.
#define WAIT4_BARRIER() do { \
    asm volatile("s_waitcnt vmcnt(4)" ::: "memory"); \
    __builtin_amdgcn_s_barrier(); } while (0)

typedef unsigned short ushort_t;
typedef __attribute__((ext_vector_type(8))) short bf16x8;
typedef __attribute__((ext_vector_type(4))) float f32x4;

__device__ __forceinline__ ushort_t f2bf(float v) {
    union { __hip_bfloat16 b; ushort_t u; } cv;
    cv.b = __float2bfloat16(v);
    return cv.u;
}

__device__ __forceinline__ void gload_lds16(const void* g, void* l) {
    __builtin_amdgcn_global_load_lds((const __attribute__((address_space(1))) void*)g,
                                     (__attribute__((address_space(3))) void*)l,
                                     16, 0, 0);
}

// broadcast lane k's float to all lanes via SGPR (VALU, not LDS unit)
__device__ __forceinline__ float bcast(float x, int k) {
    return __int_as_float(__builtin_amdgcn_readlane(__float_as_int(x), k));
}

// ---------------------------------------------------------------------------
// MEGA-INIT (r8): all 12 weight cast+transposes + prep + state0 in ONE launch.
// ---------------------------------------------------------------------------
__global__ __launch_bounds__(256)
void mega_init(const float* __restrict__ W1, const float* __restrict__ Wd1,
               const float* __restrict__ Wd2, const float* __restrict__ Wq,
               const float* __restrict__ Wk, const float* __restrict__ Wv,
               const float* __restrict__ Wg, const float* __restrict__ W2,
               ushort_t* __restrict__ W1T, ushort_t* __restrict__ Wd1T,
               ushort_t* __restrict__ Wd2T, ushort_t* __restrict__ WqT,
               ushort_t* __restrict__ WkT, ushort_t* __restrict__ WvT,
               ushort_t* __restrict__ WgT, ushort_t* __restrict__ W2Tall,
               const float* __restrict__ x, const float* __restrict__ state,
               const unsigned char* __restrict__ ns, const float* __restrict__ tmx,
               float* __restrict__ sx, ushort_t* __restrict__ xxxb,
               const int* __restrict__ len, float* __restrict__ outstate) {
    __shared__ float t[32][33];
    int bx = blockIdx.x;
    int tid = threadIdx.x;

    if (bx < 4096) {                       // ---- prep job ----
        int i4 = bx * 256 + tid;
        int idx = i4 * 4;
        int tt = idx >> 11;
        int c = idx & 2047;
        float4 xv = *(const float4*)(x + idx);
        float4 prev;
        if (ns[tt]) prev = make_float4(0.f, 0.f, 0.f, 0.f);
        else if (tt == 0) prev = *(const float4*)(state + c);
        else prev = *(const float4*)(x + idx - C_DIM);
        float4 tm = *(const float4*)(tmx + c);
        float4 s4;
        s4.x = prev.x - xv.x;  s4.y = prev.y - xv.y;
        s4.z = prev.z - xv.z;  s4.w = prev.w - xv.w;
        *(float4*)(sx + idx) = s4;
        ushort4 xb;
        xb.x = f2bf(xv.x + s4.x * tm.x);
        xb.y = f2bf(xv.y + s4.y * tm.y);
        xb.z = f2bf(xv.z + s4.z * tm.z);
        xb.w = f2bf(xv.w + s4.w * tm.w);
        *(ushort4*)(xxxb + idx) = xb;
        return;
    }
    bx -= 4096;
    if (bx < 8) {                          // ---- state0 job ----
        int c = bx * 256 + tid;
        if (c < C_DIM)
            outstate[c] = x[(size_t)(len[0] - 1) * C_DIM + c];
        return;
    }
    bx -= 8;
    // ---- cast jobs ----
    const float* W; ushort_t* WT; int K, N, nx;
    if (bx < 512)        {            W = W1;  WT = W1T;  K = 2048; N = 160;  nx = 8;  }
    else if (bx < 768)   { bx -= 512; W = Wd1; WT = Wd1T; K = 2048; N = 64;   nx = 4;  }
    else if (bx < 896)   { bx -= 768; W = Wd2; WT = Wd2T; K = 64;   N = 2048; nx = 64; }
    else if (bx < 4992)  { bx -= 896; W = Wq;  WT = WqT;  K = 2048; N = 2048; nx = 64; }
    else if (bx < 6016)  { bx -= 4992; W = Wk; WT = WkT;  K = 2048; N = 512;  nx = 16; }
    else if (bx < 7040)  { bx -= 6016; W = Wv; WT = WvT;  K = 2048; N = 512;  nx = 16; }
    else if (bx < 11136) { bx -= 7040; W = Wg; WT = WgT;  K = 2048; N = 2048; nx = 64; }
    else {
        bx -= 11136;
        int br = bx >> 6; bx &= 63;
        W = W2 + (size_t)br * 32 * C_DIM; WT = W2Tall + (size_t)br * C_DIM * 32;
        K = 32; N = 2048; nx = 64;
    }
    int n0 = (bx % nx) * 32, k0 = (bx / nx) * 32;
    int tx = tid & 31, ty = tid >> 5;
    #pragma unroll
    for (int i = 0; i < 4; ++i) {
        int k = ty + i * 8;
        float v = 0.f;
        if (n0 + tx < N) v = W[(size_t)(k0 + k) * N + n0 + tx];
        t[k][tx] = v;
    }
    __syncthreads();
    #pragma unroll
    for (int i = 0; i < 4; ++i) {
        int n = ty + i * 8;
        WT[(size_t)(n0 + n) * K + k0 + tx] = f2bf(t[tx][n]);
    }
}

// ---------------------------------------------------------------------------
// W1 split-K (r10) + T4-lite counted vmcnt (r11).
// ---------------------------------------------------------------------------
__global__ __launch_bounds__(256)
void w1_splitk(const ushort_t* __restrict__ A,      // xxxb [2048][2048]
               const ushort_t* __restrict__ BT,     // W1T  [256][2048]
               float* __restrict__ Wp) {            // [8][2048][256]
    const int lda = 2048, K = 2048;
    __shared__ ushort_t As[3][128 * 32];
    __shared__ ushort_t Bs[3][128 * 32];
    int tid = threadIdx.x;
    int wave = tid >> 6, lane = tid & 63;
    int m0 = blockIdx.y * 128, n0 = blockIdx.x * 128;
    int kbase = blockIdx.z * 256;
    float* Cf = Wp + (size_t)blockIdx.z * 2048 * 256;
    int wm = wave >> 1, wn = wave & 1;

    f32x4 acc[4][4] = {};
    int srow0 = wave * 16 + (lane >> 2);
    int schunk = lane & 3;
    int row0 = srow0, row1 = 64 + srow0;
    int gch0 = schunk ^ SWZ(row0), gch1 = schunk ^ SWZ(row1);
    const ushort_t* gA0 = A + (size_t)(m0 + row0) * lda + kbase + gch0 * 8;
    const ushort_t* gA1 = A + (size_t)(m0 + row1) * lda + kbase + gch1 * 8;
    const ushort_t* gB0 = BT + (size_t)(n0 + row0) * K + kbase + gch0 * 8;
    const ushort_t* gB1 = BT + (size_t)(n0 + row1) * K + kbase + gch1 * 8;
    int l0 = row0 * 32 + schunk * 8;
    int l1 = row1 * 32 + schunk * 8;

    const int nt = 8;                      // 256 / 32
    gload_lds16(gA0, &As[0][l0]);
    gload_lds16(gB0, &Bs[0][l0]);
    gload_lds16(gA1, &As[0][l1]);
    gload_lds16(gB1, &Bs[0][l1]);
    gload_lds16(gA0 + 32, &As[1][l0]);
    gload_lds16(gB0 + 32, &Bs[1][l0]);
    gload_lds16(gA1 + 32, &As[1][l1]);
    gload_lds16(gB1 + 32, &Bs[1][l1]);
    WAIT4_BARRIER();

    int fr = lane & 15;
    int fc = lane >> 4;
    int cur = 0;
    for (int t = 0; t < nt; ++t) {
        if (t + 2 < nt) {
            int kk = (t + 2) << 5;
            int nb = cur == 0 ? 2 : cur - 1;      // (cur+2)%3
            gload_lds16(gA0 + kk, &As[nb][l0]);
            gload_lds16(gB0 + kk, &Bs[nb][l0]);
            gload_lds16(gA1 + kk, &As[nb][l1]);
            gload_lds16(gB1 + kk, &Bs[nb][l1]);
        }
        bf16x8 af[4], bfr[4];
        #pragma unroll
        for (int mi = 0; mi < 4; ++mi) {
            int r = wm * 64 + mi * 16 + fr;
            af[mi] = *(const bf16x8*)(&As[cur][r * 32 + ((fc ^ SWZ(r)) * 8)]);
        }
        #pragma unroll
        for (int ni = 0; ni < 4; ++ni) {
            int c = wn * 64 + ni * 16 + fr;
            bfr[ni] = *(const bf16x8*)(&Bs[cur][c * 32 + ((fc ^ SWZ(c)) * 8)]);
        }
        #pragma unroll
        for (int mi = 0; mi < 4; ++mi)
            #pragma unroll
            for (int ni = 0; ni < 4; ++ni)
                acc[mi][ni] = __builtin_amdgcn_mfma_f32_16x16x32_bf16(
                    af[mi], bfr[ni], acc[mi][ni], 0, 0, 0);
        WAIT4_BARRIER();
        cur = cur == 2 ? 0 : cur + 1;
    }

    int colin = lane & 15;
    int rquad = lane >> 4;
    #pragma unroll
    for (int mi = 0; mi < 4; ++mi)
        #pragma unroll
        for (int reg = 0; reg < 4; ++reg) {
            int row = m0 + wm * 64 + mi * 16 + rquad * 4 + reg;
            #pragma unroll
            for (int ni = 0; ni < 4; ++ni) {
                int col = n0 + wn * 64 + ni * 16 + colin;
                Cf[(size_t)row * 256 + col] = acc[mi][ni][reg];
            }
        }
}

__global__ __launch_bounds__(256)
void w1_reduce(const float* __restrict__ Wp, ushort_t* __restrict__ mtlb) {
    int idx = (blockIdx.x * 256 + threadIdx.x) * 4;   // 512 blocks cover 2048*256
    float4 s = *(const float4*)(Wp + idx);
    #pragma unroll
    for (int z = 1; z < 8; ++z) {
        float4 p = *(const float4*)(Wp + (size_t)z * 2048 * 256 + idx);
        s.x += p.x; s.y += p.y; s.z += p.z; s.w += p.w;
    }
    ushort4 o;
    o.x = f2bf(tanhf(s.x)); o.y = f2bf(tanhf(s.y));
    o.z = f2bf(tanhf(s.z)); o.w = f2bf(tanhf(s.w));
    *(ushort4*)(mtlb + idx) = o;
}

// ---------------------------------------------------------------------------
// Wo GEMM split-K x2 (r12): partials into the dead U region, then reduce.
// ---------------------------------------------------------------------------
__global__ __launch_bounds__(256)
void gemm_wo_splitk(const ushort_t* __restrict__ A, const ushort_t* __restrict__ BT,
                    float* __restrict__ Wp2) {
    const int lda = 2048, K = 2048;
    __shared__ ushort_t As[3][128 * 32];
    __shared__ ushort_t Bs[3][128 * 32];
    int tid = threadIdx.x;
    int wave = tid >> 6, lane = tid & 63;
    int id = blockIdx.y * 16 + blockIdx.x;
    int xcd = id & 7, j = id >> 3;
    int m0 = ((xcd >> 1) * 4 + (j & 3)) * 128;
    int n0 = ((xcd & 1) * 8 + (j >> 2)) * 128;
    int kbase = blockIdx.z * 1024;
    float* Cf = Wp2 + (size_t)blockIdx.z * 2048 * 2048;
    int wm = wave >> 1, wn = wave & 1;

    f32x4 acc[4][4] = {};
    int srow0 = wave * 16 + (lane >> 2);
    int schunk = lane & 3;
    int row0 = srow0, row1 = 64 + srow0;
    int gch0 = schunk ^ SWZ(row0), gch1 = schunk ^ SWZ(row1);
    const ushort_t* gA0 = A + (size_t)(m0 + row0) * lda + kbase + gch0 * 8;
    const ushort_t* gA1 = A + (size_t)(m0 + row1) * lda + kbase + gch1 * 8;
    const ushort_t* gB0 = BT + (size_t)(n0 + row0) * K + kbase + gch0 * 8;
    const ushort_t* gB1 = BT + (size_t)(n0 + row1) * K + kbase + gch1 * 8;
    int l0 = row0 * 32 + schunk * 8;
    int l1 = row1 * 32 + schunk * 8;

    const int nt = 32;                     // 1024 / 32
    gload_lds16(gA0, &As[0][l0]);
    gload_lds16(gB0, &Bs[0][l0]);
    gload_lds16(gA1, &As[0][l1]);
    gload_lds16(gB1, &Bs[0][l1]);
    gload_lds16(gA0 + 32, &As[1][l0]);
    gload_lds16(gB0 + 32, &Bs[1][l0]);
    gload_lds16(gA1 + 32, &As[1][l1]);
    gload_lds16(gB1 + 32, &Bs[1][l1]);
    WAIT4_BARRIER();

    int fr = lane & 15;
    int fc = lane >> 4;
    int cur = 0;
    for (int t = 0; t < nt; ++t) {
        if (t + 2 < nt) {
            int kk = (t + 2) << 5;
            int nb = cur == 0 ? 2 : cur - 1;
            gload_lds16(gA0 + kk, &As[nb][l0]);
            gload_lds16(gB0 + kk, &Bs[nb][l0]);
            gload_lds16(gA1 + kk, &As[nb][l1]);
            gload_lds16(gB1 + kk, &Bs[nb][l1]);
        }
        bf16x8 af[4], bfr[4];
        #pragma unroll
        for (int mi = 0; mi < 4; ++mi) {
            int r = wm * 64 + mi * 16 + fr;
            af[mi] = *(const bf16x8*)(&As[cur][r * 32 + ((fc ^ SWZ(r)) * 8)]);
        }
        #pragma unroll
        for (int ni = 0; ni < 4; ++ni) {
            int c = wn * 64 + ni * 16 + fr;
            bfr[ni] = *(const bf16x8*)(&Bs[cur][c * 32 + ((fc ^ SWZ(c)) * 8)]);
        }
        #pragma unroll
        for (int mi = 0; mi < 4; ++mi)
            #pragma unroll
            for (int ni = 0; ni < 4; ++ni)
                acc[mi][ni] = __builtin_amdgcn_mfma_f32_16x16x32_bf16(
                    af[mi], bfr[ni], acc[mi][ni], 0, 0, 0);
        WAIT4_BARRIER();
        cur = cur == 2 ? 0 : cur + 1;
    }

    int colin = lane & 15;
    int rquad = lane >> 4;
    #pragma unroll
    for (int mi = 0; mi < 4; ++mi)
        #pragma unroll
        for (int reg = 0; reg < 4; ++reg) {
            int row = m0 + wm * 64 + mi * 16 + rquad * 4 + reg;
            #pragma unroll
            for (int ni = 0; ni < 4; ++ni) {
                int col = n0 + wn * 64 + ni * 16 + colin;
                Cf[(size_t)row * 2048 + col] = acc[mi][ni][reg];
            }
        }
}

__global__ __launch_bounds__(256)
void wo_reduce(const float* __restrict__ Wp2, float* __restrict__ out) {
    int idx = (blockIdx.x * 256 + threadIdx.x) * 4;   // 4096 blocks cover 2048*2048
    float4 a = *(const float4*)(Wp2 + idx);
    float4 b = *(const float4*)(Wp2 + (size_t)2048 * 2048 + idx);
    a.x += b.x; a.y += b.y; a.z += b.z; a.w += b.w;
    *(float4*)(out + idx) = a;
}

// ---------------------------------------------------------------------------
// FUSED projections (r7) + XCD swizzle (r9) + T4-lite counted vmcnt (r11).
// ---------------------------------------------------------------------------
__global__ __launch_bounds__(256)
void gemm_fused5(const ushort_t* __restrict__ xw, const ushort_t* __restrict__ xk,
                 const ushort_t* __restrict__ xv, const ushort_t* __restrict__ xr,
                 const ushort_t* __restrict__ xg,
                 const ushort_t* __restrict__ Wd1T, const ushort_t* __restrict__ WkT,
                 const ushort_t* __restrict__ WvT, const ushort_t* __restrict__ WqT,
                 const ushort_t* __restrict__ WgT,
                 ushort_t* __restrict__ tw, float* __restrict__ k0g,
                 float* __restrict__ v0g, float* __restrict__ rg,
                 float* __restrict__ gg) {
    const int K = 2048, lda = 2048;
    int id = blockIdx.y * 41 + blockIdx.x;     // 0..655
    int swz = (id & 7) * 82 + (id >> 3);       // XCD strip, 656 = 8*82
    int bx = swz >> 4;
    int m0 = (swz & 15) * 128;

    const ushort_t* A; const ushort_t* BT;
    float* Cf = nullptr; ushort_t* Cb = nullptr;
    int ldc, n0, epi;
    if (bx == 0)       { A = xw; BT = Wd1T; Cb = tw;  ldc = 128;  n0 = 0;               epi = 4; }
    else if (bx < 5)   { A = xk; BT = WkT;  Cf = k0g; ldc = 512;  n0 = (bx - 1) * 128;  epi = 0; }
    else if (bx < 9)   { A = xv; BT = WvT;  Cf = v0g; ldc = 512;  n0 = (bx - 5) * 128;  epi = 0; }
    else if (bx < 25)  { A = xr; BT = WqT;  Cf = rg;  ldc = 2048; n0 = (bx - 9) * 128;  epi = 0; }
    else               { A = xg; BT = WgT;  Cf = gg;  ldc = 2048; n0 = (bx - 25) * 128; epi = 2; }

    __shared__ ushort_t As[3][128 * 32];
    __shared__ ushort_t Bs[3][128 * 32];
    int tid = threadIdx.x;
    int wave = tid >> 6, lane = tid & 63;
    int wm = wave >> 1, wn = wave & 1;

    f32x4 acc[4][4] = {};
    int srow0 = wave * 16 + (lane >> 2);
    int schunk = lane & 3;
    int row0 = srow0, row1 = 64 + srow0;
    int gch0 = schunk ^ SWZ(row0), gch1 = schunk ^ SWZ(row1);
    const ushort_t* gA0 = A + (size_t)(m0 + row0) * lda + gch0 * 8;
    const ushort_t* gA1 = A + (size_t)(m0 + row1) * lda + gch1 * 8;
    const ushort_t* gB0 = BT + (size_t)(n0 + row0) * K + gch0 * 8;
    const ushort_t* gB1 = BT + (size_t)(n0 + row1) * K + gch1 * 8;
    int l0 = row0 * 32 + schunk * 8;
    int l1 = row1 * 32 + schunk * 8;

    const int nt = K >> 5;
    gload_lds16(gA0, &As[0][l0]);
    gload_lds16(gB0, &Bs[0][l0]);
    gload_lds16(gA1, &As[0][l1]);
    gload_lds16(gB1, &Bs[0][l1]);
    gload_lds16(gA0 + 32, &As[1][l0]);
    gload_lds16(gB0 + 32, &Bs[1][l0]);
    gload_lds16(gA1 + 32, &As[1][l1]);
    gload_lds16(gB1 + 32, &Bs[1][l1]);
    WAIT4_BARRIER();

    int fr = lane & 15;
    int fc = lane >> 4;
    int cur = 0;
    for (int t = 0; t < nt; ++t) {
        if (t + 2 < nt) {
            int kk = (t + 2) << 5;
            int nb = cur == 0 ? 2 : cur - 1;
            gload_lds16(gA0 + kk, &As[nb][l0]);
            gload_lds16(gB0 + kk, &Bs[nb][l0]);
            gload_lds16(gA1 + kk, &As[nb][l1]);
            gload_lds16(gB1 + kk, &Bs[nb][l1]);
        }
        bf16x8 af[4], bfr[4];
        #pragma unroll
        for (int mi = 0; mi < 4; ++mi) {
            int r = wm * 64 + mi * 16 + fr;
            af[mi] = *(const bf16x8*)(&As[cur][r * 32 + ((fc ^ SWZ(r)) * 8)]);
        }
        #pragma unroll
        for (int ni = 0; ni < 4; ++ni) {
            int c = wn * 64 + ni * 16 + fr;
            bfr[ni] = *(const bf16x8*)(&Bs[cur][c * 32 + ((fc ^ SWZ(c)) * 8)]);
        }
        #pragma unroll
        for (int mi = 0; mi < 4; ++mi)
            #pragma unroll
            for (int ni = 0; ni < 4; ++ni)
                acc[mi][ni] = __builtin_amdgcn_mfma_f32_16x16x32_bf16(
                    af[mi], bfr[ni], acc[mi][ni], 0, 0, 0);
        WAIT4_BARRIER();
        cur = cur == 2 ? 0 : cur + 1;
    }

    int colin = lane & 15;
    int rquad = lane >> 4;
    #pragma unroll
    for (int mi = 0; mi < 4; ++mi) {
        #pragma unroll
        for (int reg = 0; reg < 4; ++reg) {
            int row = m0 + wm * 64 + mi * 16 + rquad * 4 + reg;
            #pragma unroll
            for (int ni = 0; ni < 4; ++ni) {
                int col = n0 + wn * 64 + ni * 16 + colin;
                float v = acc[mi][ni][reg];
                if (epi == 2) v = 1.f / (1.f + __expf(-v));
                else if (epi == 4) v = tanhf(v);
                if (epi == 4) Cb[(size_t)row * ldc + col] = f2bf(v);
                else          Cf[(size_t)row * ldc + col] = v;
            }
        }
    }
}

// ---------------------------------------------------------------------------
// dec GEMM + Wo cast fused (r9).
// ---------------------------------------------------------------------------
__global__ __launch_bounds__(256)
void dec_cast(const ushort_t* __restrict__ tw, const ushort_t* __restrict__ Wd2T,
              const float* __restrict__ tdec, float* __restrict__ dec,
              const float* __restrict__ Wo, ushort_t* __restrict__ WoT) {
    int id = blockIdx.x;
    int tid = threadIdx.x;
    if (id >= 256) {                       // ---- Wo cast tile ----
        __shared__ float t[32][33];
        int c = id - 256;
        int n0 = (c & 63) * 32, k0 = (c >> 6) * 32;
        int tx = tid & 31, ty = tid >> 5;
        #pragma unroll
        for (int i = 0; i < 4; ++i) {
            int k = ty + i * 8;
            t[k][tx] = Wo[(size_t)(k0 + k) * 2048 + n0 + tx];
        }
        __syncthreads();
        #pragma unroll
        for (int i = 0; i < 4; ++i) {
            int n = ty + i * 8;
            WoT[(size_t)(n0 + n) * 2048 + k0 + tx] = f2bf(t[tx][n]);
        }
        return;
    }
    const int K = 64, lda = 128, ldc = 2048;
    __shared__ ushort_t As[2][128 * 32];
    __shared__ ushort_t Bs[2][128 * 32];
    int wave = tid >> 6, lane = tid & 63;
    int m0 = (id >> 4) * 128, n0 = (id & 15) * 128;
    int wm = wave >> 1, wn = wave & 1;

    f32x4 acc[4][4] = {};
    int srow0 = wave * 16 + (lane >> 2);
    int schunk = lane & 3;
    int row0 = srow0, row1 = 64 + srow0;
    int gch0 = schunk ^ SWZ(row0), gch1 = schunk ^ SWZ(row1);
    const ushort_t* gA0 = tw + (size_t)(m0 + row0) * lda + gch0 * 8;
    const ushort_t* gA1 = tw + (size_t)(m0 + row1) * lda + gch1 * 8;
    const ushort_t* gB0 = Wd2T + (size_t)(n0 + row0) * K + gch0 * 8;
    const ushort_t* gB1 = Wd2T + (size_t)(n0 + row1) * K + gch1 * 8;
    int l0 = row0 * 32 + schunk * 8;
    int l1 = row1 * 32 + schunk * 8;

    const int nt = K >> 5;                 // = 2
    gload_lds16(gA0, &As[0][l0]);
    gload_lds16(gB0, &Bs[0][l0]);
    gload_lds16(gA1, &As[0][l1]);
    gload_lds16(gB1, &Bs[0][l1]);
    __syncthreads();

    int fr = lane & 15;
    int fc = lane >> 4;
    int cur = 0;
    for (int t = 0; t < nt; ++t) {
        if (t + 1 < nt) {
            int kk = (t + 1) << 5;
            gload_lds16(gA0 + kk, &As[cur ^ 1][l0]);
            gload_lds16(gB0 + kk, &Bs[cur ^ 1][l0]);
            gload_lds16(gA1 + kk, &As[cur ^ 1][l1]);
            gload_lds16(gB1 + kk, &Bs[cur ^ 1][l1]);
        }
        bf16x8 af[4], bfr[4];
        #pragma unroll
        for (int mi = 0; mi < 4; ++mi) {
            int r = wm * 64 + mi * 16 + fr;
            af[mi] = *(const bf16x8*)(&As[cur][r * 32 + ((fc ^ SWZ(r)) * 8)]);
        }
        #pragma unroll
        for (int ni = 0; ni < 4; ++ni) {
            int c = wn * 64 + ni * 16 + fr;
            bfr[ni] = *(const bf16x8*)(&Bs[cur][c * 32 + ((fc ^ SWZ(c)) * 8)]);
        }
        #pragma unroll
        for (int mi = 0; mi < 4; ++mi)
            #pragma unroll
            for (int ni = 0; ni < 4; ++ni)
                acc[mi][ni] = __builtin_amdgcn_mfma_f32_16x16x32_bf16(
                    af[mi], bfr[ni], acc[mi][ni], 0, 0, 0);
        __syncthreads();
        cur ^= 1;
    }

    int colin = lane & 15;
    int rquad = lane >> 4;
    #pragma unroll
    for (int mi = 0; mi < 4; ++mi)
        #pragma unroll
        for (int reg = 0; reg < 4; ++reg) {
            int row = m0 + wm * 64 + mi * 16 + rquad * 4 + reg;
            #pragma unroll
            for (int ni = 0; ni < 4; ++ni) {
                int col = n0 + wn * 64 + ni * 16 + colin;
                dec[(size_t)row * ldc + col] = acc[mi][ni][reg] + tdec[col];
            }
        }
}

// ---------------------------------------------------------------------------
// LoRA-combine (r15): one branch per block (r13 body, 1280 blocks, 5/CU TLP)
// + XCD-grouped decode: all 5 branches of a (m,n) tile land on the SAME XCD
// so branches 2-5's x/sx tile reads are L2 hits (r9 mechanism). 1280 = 8*160;
// xcd=id%8 owns 32 complete (m,n) groups x 5 branches (bijective).
// ---------------------------------------------------------------------------
__global__ __launch_bounds__(256)
void maa_gemm(const ushort_t* __restrict__ mtlb,      // [T,256] bf16 tanh
              const ushort_t* __restrict__ W2Tall,    // [5][C][32] bf16
              const float* __restrict__ x, const float* __restrict__ sx,
              const float* __restrict__ tmr, const float* __restrict__ tmk,
              const float* __restrict__ tmv, const float* __restrict__ tmw,
              const float* __restrict__ tmg,
              ushort_t* __restrict__ xr, ushort_t* __restrict__ xk,
              ushort_t* __restrict__ xv, ushort_t* __restrict__ xw,
              ushort_t* __restrict__ xg) {
    int id = blockIdx.x;                   // 0..1279
    int xcd = id & 7, j = id >> 3;         // j in [0,160)
    int group = xcd * 32 + j / 5;          // (m,n) group in [0,256)
    int br = j % 5;
    int m0 = (group >> 4) * 128, n0 = (group & 15) * 128;

    const ushort_t* BT = W2Tall + (size_t)br * C_DIM * 32;
    const float* tm; ushort_t* dst;
    if      (br == 0) { tm = tmr; dst = xr; }
    else if (br == 1) { tm = tmk; dst = xk; }
    else if (br == 2) { tm = tmv; dst = xv; }
    else if (br == 3) { tm = tmw; dst = xw; }
    else              { tm = tmg; dst = xg; }

    __shared__ ushort_t As[128 * 32];
    __shared__ ushort_t Bs[128 * 32];
    int tid = threadIdx.x;
    int wave = tid >> 6, lane = tid & 63;
    int wm = wave >> 1, wn = wave & 1;
    int srow0 = wave * 16 + (lane >> 2);
    int schunk = lane & 3;

    #pragma unroll
    for (int jj = 0; jj < 2; ++jj) {
        int row = jj * 64 + srow0;
        int gch = schunk ^ SWZ(row);
        gload_lds16(mtlb + (size_t)(m0 + row) * 256 + br * 32 + gch * 8,
                    As + row * 32 + schunk * 8);
        gload_lds16(BT + (size_t)(n0 + row) * 32 + gch * 8,
                    Bs + row * 32 + schunk * 8);
    }
    __syncthreads();

    int fr = lane & 15;
    int fc = lane >> 4;
    f32x4 acc[4][4] = {};
    bf16x8 af[4], bfr[4];
    #pragma unroll
    for (int mi = 0; mi < 4; ++mi) {
        int r = wm * 64 + mi * 16 + fr;
        af[mi] = *(const bf16x8*)(As + r * 32 + ((fc ^ SWZ(r)) * 8));
    }
    #pragma unroll
    for (int ni = 0; ni < 4; ++ni) {
        int c = wn * 64 + ni * 16 + fr;
        bfr[ni] = *(const bf16x8*)(Bs + c * 32 + ((fc ^ SWZ(c)) * 8));
    }
    #pragma unroll
    for (int mi = 0; mi < 4; ++mi)
        #pragma unroll
        for (int ni = 0; ni < 4; ++ni)
            acc[mi][ni] = __builtin_amdgcn_mfma_f32_16x16x32_bf16(
                af[mi], bfr[ni], acc[mi][ni], 0, 0, 0);

    int colin = lane & 15;
    int rquad = lane >> 4;
    #pragma unroll
    for (int mi = 0; mi < 4; ++mi) {
        #pragma unroll
        for (int reg = 0; reg < 4; ++reg) {
            int row = m0 + wm * 64 + mi * 16 + rquad * 4 + reg;
            #pragma unroll
            for (int ni = 0; ni < 4; ++ni) {
                int col = n0 + wn * 64 + ni * 16 + colin;
                size_t idx = (size_t)row * C_DIM + col;
                float m = acc[mi][ni][reg];
                dst[idx] = f2bf(x[idx] + sx[idx] * (tm[col] + m));
            }
        }
    }
}

// ---------------------------------------------------------------------------
// Chunked scan pass 1 (r11 version): single wave, readlane bcast.
// ---------------------------------------------------------------------------
__global__ __launch_bounds__(64)
void scan_pass1(const float* __restrict__ k0, const float* __restrict__ v0,
                const float* __restrict__ dec, const unsigned char* __restrict__ ns,
                float* __restrict__ U, float* __restrict__ P) {
    int h = blockIdx.x, c = blockIdx.y, v = threadIdx.x;
    int hk = h >> 2;
    float u[64];
    #pragma unroll
    for (int k = 0; k < 64; ++k) u[k] = 0.f;
    float pk = 1.f;
    int t0 = c * CL;
    float dv_n = dec[(size_t)t0 * 2048 + h * 64 + v];
    float kv_n = k0[(size_t)t0 * 512 + hk * 64 + v];
    float vv_n = v0[(size_t)t0 * 512 + hk * 64 + v];
    unsigned char ns_n = ns[t0];
    for (int i = 0; i < CL; ++i) {
        float dv = dv_n, kv = kv_n, vv = vv_n;
        unsigned char nsv = ns_n;
        if (i + 1 < CL) {
            int t = t0 + i + 1;
            dv_n = dec[(size_t)t * 2048 + h * 64 + v];
            kv_n = k0[(size_t)t * 512 + hk * 64 + v];
            vv_n = v0[(size_t)t * 512 + hk * 64 + v];
            ns_n = ns[t];
        }
        float lw = fmaxf(-__expf(dv), -5.f);
        float ew = __expf(lw);
        float ewp = nsv ? 0.f : ew;
        float kk = kv * (1.f - ew);
        pk *= ewp;
        #pragma unroll
        for (int k = 0; k < 64; ++k) {
            float ewk = bcast(ewp, k);
            float kkk = bcast(kk, k);
            u[k] = fmaf(u[k], ewk, kkk * vv);
        }
    }
    size_t base = ((size_t)h * NC + c) * 4096;
    #pragma unroll
    for (int k = 0; k < 64; ++k) U[base + k * 64 + v] = u[k];
    P[((size_t)h * NC + c) * 64 + v] = pk;
}

// ---------------------------------------------------------------------------
// Pass 2 (elementwise-parallel): one thread per (h,k,v) state element.
// ---------------------------------------------------------------------------
__global__ __launch_bounds__(256)
void scan_pass2(float* __restrict__ U, const float* __restrict__ P,
                const float* __restrict__ state, float* __restrict__ outstate) {
    int e = blockIdx.x * 256 + threadIdx.x;      // e = h*4096 + k*64 + v
    int h = e >> 12;
    int k = (e >> 6) & 63;
    float s = state[C_DIM + e];
    int rem = e & 4095;
    #pragma unroll 4
    for (int c = 0; c < NC; ++c) {
        size_t ub = ((size_t)h * NC + c) * 4096 + rem;
        float p = P[((size_t)h * NC + c) * 64 + k];
        float u = U[ub];
        U[ub] = s;
        s = fmaf(s, p, u);
    }
    outstate[C_DIM + e] = s;
}

// ---------------------------------------------------------------------------
// Pass 3 (r11 version): single wave, readlane bcast, 4 partials.
// ---------------------------------------------------------------------------
__global__ __launch_bounds__(64)
void scan_pass3(const float* __restrict__ r, const float* __restrict__ k0,
                const float* __restrict__ v0, const float* __restrict__ dec,
                const unsigned char* __restrict__ ns,
                const float* __restrict__ Sstarts, const float* __restrict__ g,
                ushort_t* __restrict__ y0b) {
    int h = blockIdx.x, c = blockIdx.y, v = threadIdx.x;
    int hk = h >> 2;
    float s[64];
    size_t base = ((size_t)h * NC + c) * 4096;
    #pragma unroll
    for (int k = 0; k < 64; ++k) s[k] = Sstarts[base + k * 64 + v];
    int t0 = c * CL;
    float dv_n = dec[(size_t)t0 * 2048 + h * 64 + v];
    float kv_n = k0[(size_t)t0 * 512 + hk * 64 + v];
    float vv_n = v0[(size_t)t0 * 512 + hk * 64 + v];
    float rr_n = r[(size_t)t0 * 2048 + h * 64 + v];
    float gg_n = g[(size_t)t0 * 2048 + h * 64 + v];
    unsigned char ns_n = ns[t0];
    for (int i = 0; i < CL; ++i) {
        float dv = dv_n, kv = kv_n, vv = vv_n, rr = rr_n, gg = gg_n;
        unsigned char nsv = ns_n;
        if (i + 1 < CL) {
            int t = t0 + i + 1;
            dv_n = dec[(size_t)t * 2048 + h * 64 + v];
            kv_n = k0[(size_t)t * 512 + hk * 64 + v];
            vv_n = v0[(size_t)t * 512 + hk * 64 + v];
            rr_n = r[(size_t)t * 2048 + h * 64 + v];
            gg_n = g[(size_t)t * 2048 + h * 64 + v];
            ns_n = ns[t];
        }
        float lw = fmaxf(-__expf(dv), -5.f);
        float ew = __expf(lw);
        float ewl = nsv ? 0.f : ew;
        float kkl = kv * (1.f - ew);
        float o0 = 0.f, o1 = 0.f, o2 = 0.f, o3 = 0.f;
        #pragma unroll
        for (int k = 0; k < 64; k += 4) {
            float s0 = fmaf(s[k],     bcast(ewl, k),     bcast(kkl, k)     * vv); s[k]     = s0; o0 = fmaf(bcast(rr, k),     s0, o0);
            float s1 = fmaf(s[k + 1], bcast(ewl, k + 1), bcast(kkl, k + 1) * vv); s[k + 1] = s1; o1 = fmaf(bcast(rr, k + 1), s1, o1);
            float s2 = fmaf(s[k + 2], bcast(ewl, k + 2), bcast(kkl, k + 2) * vv); s[k + 2] = s2; o2 = fmaf(bcast(rr, k + 2), s2, o2);
            float s3 = fmaf(s[k + 3], bcast(ewl, k + 3), bcast(kkl, k + 3) * vv); s[k + 3] = s3; o3 = fmaf(bcast(rr, k + 3), s3, o3);
        }
        float o = (o0 + o1) + (o2 + o3);
        size_t idx = (size_t)(t0 + i) * 2048 + h * 64 + v;
        y0b[idx] = f2bf(o * gg);
    }
}

// ---------------------------------------------------------------------------
extern "C" void kernel_launch(void* const* d_in, const int* in_sizes, int n_in,
                              void* d_out, int out_size, void* d_ws, size_t ws_size,
                              hipStream_t stream) {
    const float* x     = (const float*)d_in[0];
    const float* state = (const float*)d_in[1];
    const unsigned char* ns = (const unsigned char*)d_in[2];
    const int*   len   = (const int*)d_in[3];
    const float* tmx   = (const float*)d_in[4];
    const float* tmr   = (const float*)d_in[5];
    const float* tmk   = (const float*)d_in[6];
    const float* tmv   = (const float*)d_in[7];
    const float* tmw   = (const float*)d_in[8];
    const float* tmg   = (const float*)d_in[9];
    const float* W1    = (const float*)d_in[10];   // [C,160]
    const float* W2    = (const float*)d_in[11];   // [5,32,C]
    const float* tdec  = (const float*)d_in[12];   // [C]
    const float* Wd1   = (const float*)d_in[13];   // [C,64]
    const float* Wd2   = (const float*)d_in[14];   // [64,C]
    const float* Wq    = (const float*)d_in[15];
    const float* Wk    = (const float*)d_in[16];
    const float* Wv    = (const float*)d_in[17];
    const float* Wg    = (const float*)d_in[18];
    const float* Wo    = (const float*)d_in[19];

    float* out = (float*)d_out;
    float* outstate = out + (size_t)T_DIM * C_DIM;

    // ---- workspace layout (r15; byte offsets; 122 MB total, aliased) ----
    char* wsb = (char*)d_ws;
    const size_t MB = 1024 * 1024;
    float*    sx   = (float*)(wsb + 0);            // 16 MB (dead after maa)
    float*    g    = (float*)(wsb + 0);            // 16 MB over sx
    ushort_t* xxxb = (ushort_t*)(wsb + 16 * MB);   // 8 MB; later y0b
    ushort_t* mtlb = (ushort_t*)(wsb + 24 * MB);   // 1 MB
    ushort_t* tw   = (ushort_t*)(wsb + 25 * MB);   // 0.5 MB
    float*    P    = (float*)(wsb + 25 * MB + 512 * 1024);  // 512 KB
    ushort_t* xr   = (ushort_t*)(wsb + 26 * MB);   // 8 MB (dead after fused5)
    ushort_t* xk   = (ushort_t*)(wsb + 34 * MB);   // 8 MB (dead after fused5)
    float*    dec  = (float*)(wsb + 26 * MB);      // 16 MB over xr+xk
    ushort_t* xv   = (ushort_t*)(wsb + 42 * MB);   // 8 MB (dead after fused5)
    ushort_t* WoT  = (ushort_t*)(wsb + 42 * MB);   // 8 MB over xv
    ushort_t* xw   = (ushort_t*)(wsb + 50 * MB);   // 8 MB
    ushort_t* xg   = (ushort_t*)(wsb + 58 * MB);   // 8 MB  (ends 66)
    float*    r    = (float*)(wsb + 66 * MB);      // 16 MB
    float*    Wp   = (float*)(wsb + 66 * MB);      // 16 MB over r (pre-fused5)
    float*    k0   = (float*)(wsb + 82 * MB);      // 4 MB
    float*    v0   = (float*)(wsb + 86 * MB);      // 4 MB
    ushort_t* WqT  = (ushort_t*)(wsb + 90 * MB);   // 8 MB
    ushort_t* WkT  = (ushort_t*)(wsb + 98 * MB);   // 2 MB
    ushort_t* WvT  = (ushort_t*)(wsb + 100 * MB);  // 2 MB
    ushort_t* W1T  = (ushort_t*)(wsb + 102 * MB);  // 1 MB
    ushort_t* Wd1T = (ushort_t*)(wsb + 103 * MB);  // 0.5 MB
    ushort_t* Wd2T = (ushort_t*)(wsb + 103 * MB + 512 * 1024); // 0.25 MB
    ushort_t* W2Tall = (ushort_t*)(wsb + 104 * MB); // 640 KB
    ushort_t* WgT  = (ushort_t*)(wsb + 106 * MB);  // 8 MB
    float*    U    = (float*)(wsb + 90 * MB);      // 32 MB over 90..122
    float*    Wp2  = (float*)(wsb + 90 * MB);      // 32 MB over U (post-pass3)
    ushort_t* y0b  = xxxb;

    dim3 blk(256);

    // ---- ONE init launch: 12 casts + prep + state0 ----
    mega_init<<<dim3(15560), blk, 0, stream>>>(
        W1, Wd1, Wd2, Wq, Wk, Wv, Wg, W2,
        W1T, Wd1T, Wd2T, WqT, WkT, WvT, WgT, W2Tall,
        x, state, ns, tmx, sx, xxxb, len, outstate);

    // ---- W1 LoRA via split-K ----
    w1_splitk<<<dim3(2, 16, 8), blk, 0, stream>>>(xxxb, W1T, Wp);
    w1_reduce<<<dim3(512), blk, 0, stream>>>(Wp, mtlb);
    // ---- LoRA-combine: 1280 blocks, XCD-grouped (x/sx L2-shared per tile) --
    maa_gemm<<<dim3(1280), blk, 0, stream>>>(mtlb, W2Tall, x, sx,
                                             tmr, tmk, tmv, tmw, tmg,
                                             xr, xk, xv, xw, xg);
    // ---- FUSED independent projections (XCD swizzled, counted vmcnt) ----
    gemm_fused5<<<dim3(41, 16), blk, 0, stream>>>(xw, xk, xv, xr, xg,
                                                  Wd1T, WkT, WvT, WqT, WgT,
                                                  tw, k0, v0, r, g);
    // ---- dec GEMM + Wo cast in one launch ----
    dec_cast<<<dim3(4352), blk, 0, stream>>>(tw, Wd2T, tdec, dec, Wo, WoT);
    // ---- chunked scan (single-wave r11 versions) ----
    scan_pass1<<<dim3(NH, NC), dim3(64), 0, stream>>>(k0, v0, dec, ns, U, P);
    scan_pass2<<<dim3(512), blk, 0, stream>>>(U, P, state, outstate);
    scan_pass3<<<dim3(NH, NC), dim3(64), 0, stream>>>(r, k0, v0, dec, ns, U, g, y0b);
    // ---- output: split-K x2 into dead U region, then reduce ----
    gemm_wo_splitk<<<dim3(16, 16, 2), blk, 0, stream>>>(y0b, WoT, Wp2);
    wo_reduce<<<dim3(4096), blk, 0, stream>>>(Wp2, out);
}